// Round 4
// baseline (7308.839 us; speedup 1.0000x reference)
//
#include <hip/hip_runtime.h>

typedef unsigned short u16;
typedef unsigned int u32;
using bf16x8 = __attribute__((ext_vector_type(8))) short;
using f32x4  = __attribute__((ext_vector_type(4))) float;

__device__ __forceinline__ float bf2f(u16 u) {
  union { unsigned int i; float f; } v; v.i = ((unsigned int)u) << 16; return v.f;
}
__device__ __forceinline__ u16 f2bf(float f) {
  union { float f; unsigned int i; } v; v.f = f;
  unsigned int r = v.i + 0x7fffu + ((v.i >> 16) & 1u);  // RNE
  return (u16)(r >> 16);
}

// async global->LDS, 16B per lane. LDS dest must be wave-uniform base + lane*16.
__device__ __forceinline__ void async_copy16(const u16* g, u16* l) {
  __builtin_amdgcn_global_load_lds(
      (const __attribute__((address_space(1))) void*)g,
      (__attribute__((address_space(3))) void*)l, 16, 0, 0);
}

// ---------------------------------------------------------------------------
// m97-style bf16 GEMM: C[N,M] = A[N,K] * B[M,K]^T  (B row-major [M,K])
// 128x128 tile, BK=32, 4 waves x (4x4 of 16x16x32 MFMA).
// OUTMODE: 0 = fp32 store, 1 = bf16 store.
// ---------------------------------------------------------------------------
template<int OUTMODE, int HAS_BIAS>
__global__ __launch_bounds__(256)
void gemm_tile(const u16* __restrict__ A, const u16* __restrict__ B,
               void* __restrict__ C, const float* __restrict__ bias,
               int lda, int ldb, int ldc, int K, int inner,
               long long sAo, long long sAi, long long sBo, long long sBi,
               long long sCo, long long sCi)
{
  __shared__ u16 Als[128 * 32];
  __shared__ u16 Bls[128 * 32];

  const int tid  = threadIdx.x;
  const int lane = tid & 63;
  const int wave = tid >> 6;

  const int z  = blockIdx.z;
  const int zo = z / inner;
  const int zi = z - zo * inner;

  const u16* Ab = A + zo * sAo + zi * sAi;
  const u16* Bb = B + zo * sBo + zi * sBi;

  const long long n0 = (long long)blockIdx.x * 128;
  const long long m0 = (long long)blockIdx.y * 128;

  const int c0 = tid, c1 = tid + 256;
  const int rA0 = c0 >> 2, kA0 = (c0 & 3) * 8;
  const int rA1 = c1 >> 2, kA1 = (c1 & 3) * 8;

  const u16* gA0 = Ab + (n0 + rA0) * lda + kA0;
  const u16* gA1 = Ab + (n0 + rA1) * lda + kA1;
  const u16* gB0 = Bb + (m0 + rA0) * ldb + kA0;
  const u16* gB1 = Bb + (m0 + rA1) * ldb + kA1;

  const int fr = lane & 15;
  const int fq = lane >> 4;
  const u16* Ard = &Als[(((wave >> 1) * 64) + fr) * 32 + fq * 8];
  const u16* Brd = &Bls[(((wave & 1) * 64) + fr) * 32 + fq * 8];

  f32x4 acc[4][4] = {};

  for (int kt = 0; kt < K; kt += 32) {
    async_copy16(gA0, &Als[c0 * 8]);
    async_copy16(gA1, &Als[c1 * 8]);
    async_copy16(gB0, &Bls[c0 * 8]);
    async_copy16(gB1, &Bls[c1 * 8]);
    gA0 += 32; gA1 += 32; gB0 += 32; gB1 += 32;
    __syncthreads();

    bf16x8 af[4], bfv[4];
#pragma unroll
    for (int i = 0; i < 4; ++i) af[i]  = *(const bf16x8*)(Ard + i * (16 * 32));
#pragma unroll
    for (int j = 0; j < 4; ++j) bfv[j] = *(const bf16x8*)(Brd + j * (16 * 32));
#pragma unroll
    for (int i = 0; i < 4; ++i)
#pragma unroll
      for (int j = 0; j < 4; ++j)
        acc[i][j] = __builtin_amdgcn_mfma_f32_16x16x32_bf16(af[i], bfv[j], acc[i][j], 0, 0, 0);
    __syncthreads();
  }

  const long long cb = zo * sCo + zi * sCi;
  const int wr = (wave >> 1) * 64;
  const int wc = (wave & 1) * 64;
#pragma unroll
  for (int i = 0; i < 4; ++i) {
#pragma unroll
    for (int r = 0; r < 4; ++r) {
      const long long row = n0 + wr + i * 16 + fq * 4 + r;
#pragma unroll
      for (int j = 0; j < 4; ++j) {
        const long long col = m0 + wc + j * 16 + fr;
        float v = acc[i][j][r];
        if (HAS_BIAS) v += bias[col];
        const long long idx = cb + row * ldc + col;
        if (OUTMODE == 0) ((float*)C)[idx] = v;
        else              ((u16*)C)[idx] = f2bf(v);
      }
    }
  }
}

template<int OUT, int BIAS>
static inline void run_gemm(hipStream_t st,
    const u16* A, const u16* B, void* C, const float* bias,
    int N, int M, int K, int lda, int ldb, int ldc,
    int batch, int inner,
    long long sAo, long long sAi, long long sBo, long long sBi,
    long long sCo, long long sCi)
{
  dim3 g(N / 128, M / 128, batch);
  gemm_tile<OUT, BIAS><<<g, dim3(256), 0, st>>>(
      A, B, C, bias, lda, ldb, ldc, K, inner, sAo, sAi, sBo, sBi, sCo, sCi);
}

// ---------------------------------------------------------------------------
// Grouped MoE fc1: all 8 experts (6 spec gathered + 2 shared identity) in one
// dispatch. Row space = padded concat of expert lists (128-aligned offsets).
// Computes gelu(h[tok] @ W1e[ff0:ff0+512].T + b1e) -> hid[globalrow][512].
// ---------------------------------------------------------------------------
__global__ __launch_bounds__(256)
void moe_fc1_k(const u16* __restrict__ A, const u16* __restrict__ W,
               const float* __restrict__ sb, const float* __restrict__ hb,
               const int* __restrict__ idx, const int* __restrict__ cnt,
               const int* __restrict__ poff,
               u16* __restrict__ hid, int ff0)
{
  __shared__ u16 Als[128 * 32];
  __shared__ u16 Bls[128 * 32];

  const int tid  = threadIdx.x;
  const int lane = tid & 63;
  const int wave = tid >> 6;

  const int row0 = blockIdx.x * 128;
  if (row0 >= poff[8]) return;
  int e = 0;
  while (row0 >= poff[e + 1]) ++e;
  const int r0 = row0 - poff[e];
  const int ce = cnt[e];
  if (r0 >= ce) return;
  const int* gi = idx + e * 16384;

  const int m0 = blockIdx.y * 128;                      // 0..384
  const u16* Wb = W + (size_t)e * 2048 * 512 + (size_t)(ff0 + m0) * 512;
  const float* bias = (e < 6 ? sb + e * 2048 : hb + (e - 6) * 2048) + ff0;

  const int c0 = tid, c1 = tid + 256;
  const int rA0 = c0 >> 2, kA0 = (c0 & 3) * 8;
  const int rA1 = c1 >> 2, kA1 = (c1 & 3) * 8;

  const int t0 = (r0 + rA0 < ce) ? gi[r0 + rA0] : gi[r0];
  const int t1 = (r0 + rA1 < ce) ? gi[r0 + rA1] : gi[r0];
  const u16* gA0 = A + (size_t)t0 * 512 + kA0;
  const u16* gA1 = A + (size_t)t1 * 512 + kA1;
  const u16* gB0 = Wb + (size_t)rA0 * 512 + kA0;
  const u16* gB1 = Wb + (size_t)rA1 * 512 + kA1;

  const int fr = lane & 15;
  const int fq = lane >> 4;
  const u16* Ard = &Als[(((wave >> 1) * 64) + fr) * 32 + fq * 8];
  const u16* Brd = &Bls[(((wave & 1) * 64) + fr) * 32 + fq * 8];

  f32x4 acc[4][4] = {};

  for (int kt = 0; kt < 512; kt += 32) {
    async_copy16(gA0, &Als[c0 * 8]);
    async_copy16(gA1, &Als[c1 * 8]);
    async_copy16(gB0, &Bls[c0 * 8]);
    async_copy16(gB1, &Bls[c1 * 8]);
    gA0 += 32; gA1 += 32; gB0 += 32; gB1 += 32;
    __syncthreads();

    bf16x8 af[4], bfv[4];
#pragma unroll
    for (int i = 0; i < 4; ++i) af[i]  = *(const bf16x8*)(Ard + i * (16 * 32));
#pragma unroll
    for (int j = 0; j < 4; ++j) bfv[j] = *(const bf16x8*)(Brd + j * (16 * 32));
#pragma unroll
    for (int i = 0; i < 4; ++i)
#pragma unroll
      for (int j = 0; j < 4; ++j)
        acc[i][j] = __builtin_amdgcn_mfma_f32_16x16x32_bf16(af[i], bfv[j], acc[i][j], 0, 0, 0);
    __syncthreads();
  }

  const int wr = (wave >> 1) * 64;
  const int wc = (wave & 1) * 64;
#pragma unroll
  for (int i = 0; i < 4; ++i) {
#pragma unroll
    for (int r = 0; r < 4; ++r) {
      const long long row = row0 + wr + i * 16 + fq * 4 + r;
#pragma unroll
      for (int j = 0; j < 4; ++j) {
        const int col = m0 + wc + j * 16 + fr;
        float v = acc[i][j][r] + bias[col];
        v = 0.5f * v * (1.f + erff(v * 0.70710678118654752f));
        hid[row * 512 + col] = f2bf(v);
      }
    }
  }
}

// ---------------------------------------------------------------------------
// Grouped MoE fc2 (FF quarter): macc[tok] += scale_e[tok] *
//      (hid_row @ W2e[:, ff0:ff0+512].T + (ff0==0 ? b2e : 0))
// ---------------------------------------------------------------------------
__global__ __launch_bounds__(256)
void moe_fc2_k(const u16* __restrict__ hid, const u16* __restrict__ W,
               const float* __restrict__ sb, const float* __restrict__ hb,
               const float* __restrict__ comb, const float* __restrict__ sp,
               const int* __restrict__ idx, const int* __restrict__ cnt,
               const int* __restrict__ poff,
               float* __restrict__ macc, int ff0)
{
  __shared__ u16 Als[128 * 32];
  __shared__ u16 Bls[128 * 32];

  const int tid  = threadIdx.x;
  const int lane = tid & 63;
  const int wave = tid >> 6;

  const int row0 = blockIdx.x * 128;
  if (row0 >= poff[8]) return;
  int e = 0;
  while (row0 >= poff[e + 1]) ++e;
  const int r0 = row0 - poff[e];
  const int ce = cnt[e];
  if (r0 >= ce) return;
  const int* gi = idx + e * 16384;

  const int m0 = blockIdx.y * 128;                      // 0..384
  const u16* Wb = W + (size_t)e * 512 * 2048 + (size_t)m0 * 2048 + ff0;
  const float* bias = (e < 6 ? sb + e * 512 : hb + (e - 6) * 512);

  const int c0 = tid, c1 = tid + 256;
  const int rA0 = c0 >> 2, kA0 = (c0 & 3) * 8;
  const int rA1 = c1 >> 2, kA1 = (c1 & 3) * 8;

  const u16* gA0 = hid + (size_t)(row0 + rA0) * 512 + kA0;
  const u16* gA1 = hid + (size_t)(row0 + rA1) * 512 + kA1;
  const u16* gB0 = Wb + (size_t)rA0 * 2048 + kA0;
  const u16* gB1 = Wb + (size_t)rA1 * 2048 + kA1;

  const int fr = lane & 15;
  const int fq = lane >> 4;
  const u16* Ard = &Als[(((wave >> 1) * 64) + fr) * 32 + fq * 8];
  const u16* Brd = &Bls[(((wave & 1) * 64) + fr) * 32 + fq * 8];

  f32x4 acc[4][4] = {};

  for (int kt = 0; kt < 512; kt += 32) {
    async_copy16(gA0, &Als[c0 * 8]);
    async_copy16(gA1, &Als[c1 * 8]);
    async_copy16(gB0, &Bls[c0 * 8]);
    async_copy16(gB1, &Bls[c1 * 8]);
    gA0 += 32; gA1 += 32; gB0 += 32; gB1 += 32;
    __syncthreads();

    bf16x8 af[4], bfv[4];
#pragma unroll
    for (int i = 0; i < 4; ++i) af[i]  = *(const bf16x8*)(Ard + i * (16 * 32));
#pragma unroll
    for (int j = 0; j < 4; ++j) bfv[j] = *(const bf16x8*)(Brd + j * (16 * 32));
#pragma unroll
    for (int i = 0; i < 4; ++i)
#pragma unroll
      for (int j = 0; j < 4; ++j)
        acc[i][j] = __builtin_amdgcn_mfma_f32_16x16x32_bf16(af[i], bfv[j], acc[i][j], 0, 0, 0);
    __syncthreads();
  }

  const int wr = (wave >> 1) * 64;
  const int wc = (wave & 1) * 64;
#pragma unroll
  for (int i = 0; i < 4; ++i) {
#pragma unroll
    for (int r = 0; r < 4; ++r) {
      const int lr = r0 + wr + i * 16 + fq * 4 + r;
      if (lr >= ce) continue;
      const int tok = gi[lr];
      const float rs = (e < 6) ? comb[(size_t)tok * 6 + e] : sp[(size_t)tok * 2 + (e - 6)];
#pragma unroll
      for (int j = 0; j < 4; ++j) {
        const int col = m0 + wc + j * 16 + fr;
        float v = acc[i][j][r];
        if (ff0 == 0) v += bias[col];
        atomicAdd(&macc[(size_t)tok * 512 + col], rs * v);
      }
    }
  }
}

// ---------------------------------------------------------------------------
// elementwise / small kernels
// ---------------------------------------------------------------------------
__global__ void cast_bf16_k(const float* __restrict__ s, u16* __restrict__ d, long long n)
{
  long long i = (long long)blockIdx.x * blockDim.x + threadIdx.x;
  const long long stride = (long long)gridDim.x * blockDim.x;
  for (; i < n; i += stride) d[i] = f2bf(s[i]);
}

// dst [4][8][1M] <- spec [4][6][1M] , shared [4][2][1M]
__global__ void cast_moe_w_k(const float* __restrict__ spec,
                             const float* __restrict__ shr,
                             u16* __restrict__ dst)
{
  long long i = (long long)blockIdx.x * blockDim.x + threadIdx.x;
  const long long stride = (long long)gridDim.x * blockDim.x;
  const long long n = 4LL * 8 * 1048576;
  for (; i < n; i += stride) {
    const long long l = i >> 23;
    const long long r = i & ((1LL << 23) - 1);
    const long long e = r >> 20;
    const long long o = r & 1048575;
    const float v = (e < 6) ? spec[(l * 6 + e) * 1048576 + o]
                            : shr[(l * 2 + (e - 6)) * 1048576 + o];
    dst[i] = f2bf(v);
  }
}

__global__ void transpose_f32_k(const float* __restrict__ s, float* __restrict__ d,
                                int rows, int cols)
{
  int i = blockIdx.x * blockDim.x + threadIdx.x;
  if (i < rows * cols) { int r = i / cols, c = i - r * cols; d[c * rows + r] = s[i]; }
}

__global__ __launch_bounds__(64)
void tokenizer_k(const float* __restrict__ x, const float* __restrict__ w1T,
                 const float* __restrict__ b1, const float* __restrict__ w2T,
                 const float* __restrict__ b2, u16* __restrict__ z)
{
  const int token = blockIdx.x;
  const int b = token >> 10, s = token & 1023;
  const int ph = s >> 5, pw = s & 31;
  const int lane = threadIdx.x;
  __shared__ float t[320];
  __shared__ float z1[64];
  const int py = lane >> 3, px = lane & 7;
  const float* xp = x + (size_t)b * 5 * 65536 + (size_t)(ph * 8 + py) * 256 + pw * 8 + px;
#pragma unroll
  for (int c = 0; c < 5; ++c) t[c * 64 + lane] = xp[(size_t)c * 65536];
  __syncthreads();
  float acc = b1[lane];
  for (int k = 0; k < 320; ++k) acc = fmaf(t[k], w1T[k * 64 + lane], acc);
  z1[lane] = fmaxf(acc, 0.f);
  __syncthreads();
  float a0 = b2[lane], a1 = b2[lane + 64];
  for (int k = 0; k < 64; ++k) {
    const float zv = z1[k];
    a0 = fmaf(zv, w2T[k * 128 + lane], a0);
    a1 = fmaf(zv, w2T[k * 128 + lane + 64], a1);
  }
  a0 = fmaxf(a0, 0.f); a1 = fmaxf(a1, 0.f);
  const float fs = (float)s;
  const int d0 = lane, d1 = lane + 64;
  const float div0 = expf(-logf(10000.f) * (float)(d0 & ~1) / 128.f);
  const float div1 = expf(-logf(10000.f) * (float)(d1 & ~1) / 128.f);
  const float pe0 = (d0 & 1) ? cosf(fs * div0) : sinf(fs * div0);
  const float pe1 = (d1 & 1) ? cosf(fs * div1) : sinf(fs * div1);
  z[(size_t)token * 128 + d0] = f2bf(a0 + pe0);
  z[(size_t)token * 128 + d1] = f2bf(a1 + pe1);
}

__global__ void transpose_v_k(const u16* __restrict__ qkv, u16* __restrict__ vT)
{
  __shared__ u16 tile[32][33];
  const int z = blockIdx.z;
  const int b = z >> 2, hh = z & 3;
  const int s0 = blockIdx.x * 32, d0 = blockIdx.y * 32;
  const int tx = threadIdx.x;
  for (int i = threadIdx.y; i < 32; i += 8)
    tile[i][tx] = qkv[(long long)(b * 1024 + s0 + i) * 1536 + 1024 + hh * 128 + d0 + tx];
  __syncthreads();
  for (int j = threadIdx.y; j < 32; j += 8)
    vT[((long long)z * 128 + d0 + j) * 1024 + s0 + tx] = tile[tx][j];
}

// in-place row softmax (1024 cols, bf16), vectorized uint2 (4 elems/thread)
__global__ __launch_bounds__(256)
void softmax_k(u16* __restrict__ P, float scale)
{
  const long long row = blockIdx.x;
  uint2* p = (uint2*)(P + row * 1024);
  const int tid = threadIdx.x;
  uint2 d = p[tid];
  float v[4];
  v[0] = bf2f((u16)(d.x & 0xffff)) * scale;
  v[1] = bf2f((u16)(d.x >> 16)) * scale;
  v[2] = bf2f((u16)(d.y & 0xffff)) * scale;
  v[3] = bf2f((u16)(d.y >> 16)) * scale;
  __shared__ float red[256];
  float mx = fmaxf(fmaxf(v[0], v[1]), fmaxf(v[2], v[3]));
  red[tid] = mx; __syncthreads();
  for (int s = 128; s > 0; s >>= 1) { if (tid < s) red[tid] = fmaxf(red[tid], red[tid + s]); __syncthreads(); }
  mx = red[0]; __syncthreads();
  float sum = 0.f;
#pragma unroll
  for (int j = 0; j < 4; ++j) { v[j] = expf(v[j] - mx); sum += v[j]; }
  red[tid] = sum; __syncthreads();
  for (int s = 128; s > 0; s >>= 1) { if (tid < s) red[tid] += red[tid + s]; __syncthreads(); }
  const float inv = 1.f / red[0];
  uint2 o;
  o.x = (u32)f2bf(v[0] * inv) | ((u32)f2bf(v[1] * inv) << 16);
  o.y = (u32)f2bf(v[2] * inv) | ((u32)f2bf(v[3] * inv) << 16);
  p[tid] = o;
}

__global__ __launch_bounds__(256)
void ln_add_k(float* __restrict__ h, const float* __restrict__ a,
              const float* __restrict__ g, const float* __restrict__ b,
              u16* __restrict__ hbf)
{
  const long long t = blockIdx.x;
  const int tid = threadIdx.x;
  float* hp = h + t * 512;
  const float* ap = a + t * 512;
  const float x0 = hp[tid] + ap[tid];
  const float x1 = hp[tid + 256] + ap[tid + 256];
  __shared__ float r1[256], r2[256];
  r1[tid] = x0 + x1; r2[tid] = x0 * x0 + x1 * x1;
  __syncthreads();
  for (int s = 128; s > 0; s >>= 1) { if (tid < s) { r1[tid] += r1[tid + s]; r2[tid] += r2[tid + s]; } __syncthreads(); }
  const float mean = r1[0] * (1.f / 512.f);
  const float var  = r2[0] * (1.f / 512.f) - mean * mean;
  const float rstd = rsqrtf(var + 1e-5f);
  const float y0 = (x0 - mean) * rstd * g[tid] + b[tid];
  const float y1 = (x1 - mean) * rstd * g[tid + 256] + b[tid + 256];
  hp[tid] = y0; hp[tid + 256] = y1;
  hbf[t * 512 + tid] = f2bf(y0); hbf[t * 512 + tid + 256] = f2bf(y1);
}

__global__ __launch_bounds__(256)
void merge_ln_k(float* __restrict__ h, const float* __restrict__ macc,
                const float* __restrict__ g1, const float* __restrict__ b1,
                const float* __restrict__ g2, const float* __restrict__ b2,
                u16* __restrict__ hbf)
{
  const long long t = blockIdx.x;
  const int tid = threadIdx.x;
  float* hp = h + t * 512;
  const float* mp = macc + t * 512;
  const float hx0 = hp[tid], hx1 = hp[tid + 256];
  const float s0 = hx0 + mp[tid], s1 = hx1 + mp[tid + 256];
  __shared__ float r1[256], r2[256];
  r1[tid] = s0 + s1; r2[tid] = s0 * s0 + s1 * s1;
  __syncthreads();
  for (int s = 128; s > 0; s >>= 1) { if (tid < s) { r1[tid] += r1[tid + s]; r2[tid] += r2[tid + s]; } __syncthreads(); }
  float mean = r1[0] * (1.f / 512.f);
  float var  = r2[0] * (1.f / 512.f) - mean * mean;
  float rstd = rsqrtf(var + 1e-5f);
  const float m0v = (s0 - mean) * rstd * g1[tid] + b1[tid];
  const float m1v = (s1 - mean) * rstd * g1[tid + 256] + b1[tid + 256];
  const float z0 = hx0 + m0v, z1 = hx1 + m1v;
  __syncthreads();
  r1[tid] = z0 + z1; r2[tid] = z0 * z0 + z1 * z1;
  __syncthreads();
  for (int s = 128; s > 0; s >>= 1) { if (tid < s) { r1[tid] += r1[tid + s]; r2[tid] += r2[tid + s]; } __syncthreads(); }
  mean = r1[0] * (1.f / 512.f);
  var  = r2[0] * (1.f / 512.f) - mean * mean;
  rstd = rsqrtf(var + 1e-5f);
  const float y0 = (z0 - mean) * rstd * g2[tid] + b2[tid];
  const float y1 = (z1 - mean) * rstd * g2[tid + 256] + b2[tid + 256];
  hp[tid] = y0; hp[tid + 256] = y1;
  hbf[t * 512 + tid] = f2bf(y0); hbf[t * 512 + tid + 256] = f2bf(y1);
}

// router: softmax+top2 comb, shared softmax sp, direct list append + identity
__global__ __launch_bounds__(64)
void router_k(const float* __restrict__ h, const float* __restrict__ sw,
              const float* __restrict__ hw, float* __restrict__ comb,
              float* __restrict__ sp, int* __restrict__ cnt, int* __restrict__ idx)
{
  const long long t = blockIdx.x;
  const int lane = threadIdx.x;
  const float* hp = h + t * 512;
  float v[8];
#pragma unroll
  for (int j = 0; j < 8; ++j) v[j] = hp[lane + j * 64];

  float lg[6];
#pragma unroll
  for (int e = 0; e < 6; ++e) {
    const float* w = sw + e * 512;
    float d = 0.f;
#pragma unroll
    for (int j = 0; j < 8; ++j) d += v[j] * w[lane + j * 64];
#pragma unroll
    for (int off = 32; off > 0; off >>= 1) d += __shfl_xor(d, off);
    lg[e] = d;
  }
  float mx = lg[0];
#pragma unroll
  for (int e = 1; e < 6; ++e) mx = fmaxf(mx, lg[e]);
  float pp[6]; float sum = 0.f;
#pragma unroll
  for (int e = 0; e < 6; ++e) { pp[e] = expf(lg[e] - mx); sum += pp[e]; }
  const float inv = 1.f / sum;
#pragma unroll
  for (int e = 0; e < 6; ++e) pp[e] *= inv;

  int i1 = 0; float p1 = pp[0];
#pragma unroll
  for (int e = 1; e < 6; ++e) if (pp[e] > p1) { p1 = pp[e]; i1 = e; }
  int i2 = -1; float p2 = -1.f;
#pragma unroll
  for (int e = 0; e < 6; ++e) if (e != i1 && pp[e] > p2) { p2 = pp[e]; i2 = e; }
  const float den = 1.f / (p1 + p2 + 1e-9f);
  if (lane == 0) {
#pragma unroll
    for (int e = 0; e < 6; ++e)
      comb[t * 6 + e] = (e == i1) ? p1 * den : ((e == i2) ? p2 * den : 0.f);
    int p = atomicAdd(&cnt[i1], 1); idx[i1 * 16384 + p] = (int)t;
    p = atomicAdd(&cnt[i2], 1);     idx[i2 * 16384 + p] = (int)t;
    idx[6 * 16384 + t] = (int)t;
    idx[7 * 16384 + t] = (int)t;
  }

  float l0 = 0.f, l1 = 0.f;
#pragma unroll
  for (int j = 0; j < 8; ++j) {
    l0 += v[j] * hw[lane + j * 64];
    l1 += v[j] * hw[512 + lane + j * 64];
  }
#pragma unroll
  for (int off = 32; off > 0; off >>= 1) { l0 += __shfl_xor(l0, off); l1 += __shfl_xor(l1, off); }
  const float m2 = fmaxf(l0, l1);
  const float e0 = expf(l0 - m2), e1 = expf(l1 - m2);
  const float si = 1.f / (e0 + e1);
  if (lane == 0) { sp[t * 2 + 0] = e0 * si; sp[t * 2 + 1] = e1 * si; }
}

// set shared counts + padded prefix offsets (single thread, 8 entries)
__global__ void offsets_k(int* __restrict__ cnt, int* __restrict__ poff)
{
  if (threadIdx.x == 0 && blockIdx.x == 0) {
    cnt[6] = 16384; cnt[7] = 16384;
    int o = 0; poff[0] = 0;
    for (int e = 0; e < 8; ++e) { o += (cnt[e] + 127) & ~127; poff[e + 1] = o; }
  }
}

__global__ __launch_bounds__(256)
void pool_cls_k(const float* __restrict__ h, const float* __restrict__ cw,
                const float* __restrict__ cb, float* __restrict__ out)
{
  const int b = blockIdx.x;
  const int tid = threadIdx.x;
  const float* hp = h + (size_t)b * 1024 * 512;
  float s0 = 0.f, s1 = 0.f;
  for (int s = 0; s < 1024; ++s) {
    s0 += hp[(size_t)s * 512 + tid];
    s1 += hp[(size_t)s * 512 + tid + 256];
  }
  __shared__ float pooled[512];
  pooled[tid] = s0 * (1.f / 1024.f); pooled[tid + 256] = s1 * (1.f / 1024.f);
  __syncthreads();
  __shared__ float red[256];
  for (int c = 0; c < 2; ++c) {
    const float d = pooled[tid] * cw[c * 512 + tid] + pooled[tid + 256] * cw[c * 512 + tid + 256];
    red[tid] = d; __syncthreads();
    for (int s = 128; s > 0; s >>= 1) { if (tid < s) red[tid] += red[tid + s]; __syncthreads(); }
    if (tid == 0) out[b * 2 + c] = red[0] + cb[c];
    __syncthreads();
  }
}

// ---------------------------------------------------------------------------
extern "C" void kernel_launch(void* const* d_in, const int* in_sizes, int n_in,
                              void* d_out, int out_size, void* d_ws, size_t ws_size,
                              hipStream_t stream)
{
  (void)in_sizes; (void)n_in; (void)out_size;
  const float* x      = (const float*)d_in[0];
  const float* tok_w1 = (const float*)d_in[1];
  const float* tok_b1 = (const float*)d_in[2];
  const float* tok_w2 = (const float*)d_in[3];
  const float* tok_b2 = (const float*)d_in[4];
  const float* proj_w = (const float*)d_in[5];
  const float* proj_b = (const float*)d_in[6];
  const float* wqkv   = (const float*)d_in[7];
  const float* bqkv   = (const float*)d_in[8];
  const float* wo     = (const float*)d_in[9];
  const float* bo     = (const float*)d_in[10];
  const float* ln1_g  = (const float*)d_in[11];
  const float* ln1_b  = (const float*)d_in[12];
  const float* srw    = (const float*)d_in[13];
  const float* sfc1w  = (const float*)d_in[14];
  const float* sfc1b  = (const float*)d_in[15];
  const float* sfc2w  = (const float*)d_in[16];
  const float* sfc2b  = (const float*)d_in[17];
  const float* hrw    = (const float*)d_in[18];
  const float* hfc1w  = (const float*)d_in[19];
  const float* hfc1b  = (const float*)d_in[20];
  const float* hfc2w  = (const float*)d_in[21];
  const float* hfc2b  = (const float*)d_in[22];
  const float* lnm_g  = (const float*)d_in[23];
  const float* lnm_b  = (const float*)d_in[24];
  const float* ln2_g  = (const float*)d_in[25];
  const float* ln2_b  = (const float*)d_in[26];
  const float* cls_w  = (const float*)d_in[27];
  const float* cls_b  = (const float*)d_in[28];

  char* ws = (char*)d_ws;
  size_t off = 0;
  auto alloc = [&](size_t bytes) -> char* {
    char* p = ws + off;
    off = (off + bytes + 255) & ~(size_t)255;
    return p;
  };

  u16* proj_bf = (u16*)alloc((size_t)512 * 128 * 2);
  u16* qkvw_bf = (u16*)alloc((size_t)4 * 1536 * 512 * 2);
  u16* wow_bf  = (u16*)alloc((size_t)4 * 512 * 512 * 2);
  u16* w1comb  = (u16*)alloc((size_t)4 * 8 * 2048 * 512 * 2);   // [l][e][FF][HS]
  u16* w2comb  = (u16*)alloc((size_t)4 * 8 * 512 * 2048 * 2);   // [l][e][HS][FF]
  float* w1T   = (float*)alloc((size_t)320 * 64 * 4);
  float* w2T   = (float*)alloc((size_t)64 * 128 * 4);
  u16* zbf     = (u16*)alloc((size_t)16384 * 128 * 2);
  float* h     = (float*)alloc((size_t)16384 * 512 * 4);
  u16* hbf     = (u16*)alloc((size_t)16384 * 512 * 2);
  u16* vT      = (u16*)alloc((size_t)64 * 128 * 1024 * 2);
  u16* abf     = (u16*)alloc((size_t)16384 * 512 * 2);
  int* cnt     = (int*)alloc((size_t)8 * 4);
  int* poff    = (int*)alloc((size_t)9 * 4);
  int* idx     = (int*)alloc((size_t)8 * 16384 * 4);
  // regionA (68.2MB): scores chunk (67.1MB) / wo-out fp32 (33.6MB) / hid (68.2MB)
  char* regA   = alloc((size_t)66560 * 512 * 2);
  // regionB (50.3MB): qkv bf16 / (macc fp32 + comb + sp)
  char* regB   = alloc((size_t)16384 * 1536 * 2);
  u16*   scores = (u16*)regA;
  float* af32   = (float*)regA;
  u16*   hid    = (u16*)regA;
  u16*   qkv    = (u16*)regB;
  float* macc   = (float*)regB;
  float* comb   = (float*)(regB + (size_t)16384 * 512 * 4);
  float* sp     = (float*)(regB + (size_t)16384 * 512 * 4 + (size_t)16384 * 6 * 4);

  if (off > ws_size) return;   // diagnostic guard: fail loud (absmax) not crash

  // ---- weight prep ----
  cast_bf16_k<<<4096, 256, 0, stream>>>(proj_w, proj_bf, 65536LL);
  cast_bf16_k<<<4096, 256, 0, stream>>>(wqkv,   qkvw_bf, 3145728LL);
  cast_bf16_k<<<4096, 256, 0, stream>>>(wo,     wow_bf,  1048576LL);
  cast_moe_w_k<<<8192, 256, 0, stream>>>(sfc1w, hfc1w, w1comb);
  cast_moe_w_k<<<8192, 256, 0, stream>>>(sfc2w, hfc2w, w2comb);
  transpose_f32_k<<<(20480 + 255) / 256, 256, 0, stream>>>(tok_w1, w1T, 64, 320);
  transpose_f32_k<<<(8192 + 255) / 256, 256, 0, stream>>>(tok_w2, w2T, 128, 64);

  // ---- tokenizer + PE -> z, proj -> h ----
  tokenizer_k<<<16384, 64, 0, stream>>>(x, w1T, tok_b1, w2T, tok_b2, zbf);
  run_gemm<0, 1>(stream, zbf, proj_bf, h, proj_b,
                 16384, 512, 128, 128, 128, 512, 1, 1, 0, 0, 0, 0, 0, 0);
  cast_bf16_k<<<4096, 256, 0, stream>>>(h, hbf, 8388608LL);

  for (int l = 0; l < 4; ++l) {
    run_gemm<1, 1>(stream, hbf, qkvw_bf + (size_t)l * 1536 * 512, qkv,
                   bqkv + l * 1536,
                   16384, 1536, 512, 512, 512, 1536, 1, 1, 0, 0, 0, 0, 0, 0);
    transpose_v_k<<<dim3(32, 4, 64), dim3(32, 8), 0, stream>>>(qkv, vT);
    for (int c = 0; c < 2; ++c) {
      const u16* qb = qkv + (size_t)c * 8 * 1024 * 1536;
      run_gemm<1, 0>(stream, qb, qb + 512, scores, nullptr,
                     1024, 1024, 128, 1536, 1536, 1024, 32, 4,
                     1024LL * 1536, 128, 1024LL * 1536, 128,
                     4LL * 1024 * 1024, 1024LL * 1024);
      softmax_k<<<32768, 256, 0, stream>>>(scores, 0.08838834764831845f);
      run_gemm<1, 0>(stream, scores, vT + (size_t)c * 8 * 4 * 128 * 1024,
                     abf + (size_t)c * 8 * 1024 * 512, nullptr,
                     1024, 128, 1024, 1024, 1024, 512, 32, 4,
                     4LL * 1024 * 1024, 1024LL * 1024,
                     4LL * 128 * 1024, 128LL * 1024,
                     1024LL * 512, 128);
    }
    run_gemm<0, 1>(stream, abf, wow_bf + (size_t)l * 512 * 512, af32,
                   bo + l * 512,
                   16384, 512, 512, 512, 512, 512, 1, 1, 0, 0, 0, 0, 0, 0);
    hipMemsetAsync(macc, 0, (size_t)16384 * 512 * 4, stream);   // qkv dead
    hipMemsetAsync(cnt, 0, 8 * sizeof(int), stream);
    ln_add_k<<<16384, 256, 0, stream>>>(h, af32, ln1_g + l * 512, ln1_b + l * 512, hbf);
    router_k<<<16384, 64, 0, stream>>>(h, srw + (size_t)l * 6 * 512,
                                       hrw + (size_t)l * 2 * 512, comb, sp, cnt, idx);
    offsets_k<<<1, 64, 0, stream>>>(cnt, poff);
    // grouped MoE: 4 FF-quarters x (fc1 + fc2), all 8 experts per dispatch
    for (int ffq = 0; ffq < 4; ++ffq) {
      moe_fc1_k<<<dim3(520, 4), dim3(256), 0, stream>>>(
          hbf, w1comb + (size_t)l * 8 * 2048 * 512,
          sfc1b + (size_t)l * 6 * 2048, hfc1b + (size_t)l * 2 * 2048,
          idx, cnt, poff, hid, ffq * 512);
      moe_fc2_k<<<dim3(520, 4), dim3(256), 0, stream>>>(
          hid, w2comb + (size_t)l * 8 * 512 * 2048,
          sfc2b + (size_t)l * 6 * 512, hfc2b + (size_t)l * 2 * 512,
          comb, sp, idx, cnt, poff, macc, ffq * 512);
    }
    merge_ln_k<<<16384, 256, 0, stream>>>(h, macc, lnm_g + l * 512, lnm_b + l * 512,
                                          ln2_g + l * 512, ln2_b + l * 512, hbf);
  }

  pool_cls_k<<<16, 256, 0, stream>>>(h, cls_w, cls_b, (float*)d_out);
}